// Round 7
// baseline (170.817 us; speedup 1.0000x reference)
//
#include <hip/hip_runtime.h>

// MHSA: B=2, S=2048, D=1024, H=16, hd=64. fp32 in/out, bf16 MFMA internally.
// 3 kernels (was 4 — cvt_all deleted, conversion fused into GEMM staging):
//   gemm_qkv (fp32 in, reg-staged cvt, 128x192 tile, 512 blocks = 2/CU, 1 barrier/K-step)
//   attn_flash (r4/r6 verified: 8-wave 4qgx2kg, P in registers, XCD-local grid)
//   gemm_out (fp32 Wout in, reg-staged cvt, 64x128 tile, +bias)

typedef __attribute__((ext_vector_type(8))) short short8;
typedef __attribute__((ext_vector_type(4))) float f32x4;
typedef __attribute__((ext_vector_type(2))) unsigned int uint32x2;
typedef unsigned short ushort_t;
typedef unsigned int uint32;

#define AS1 __attribute__((address_space(1)))
#define AS3 __attribute__((address_space(3)))

__device__ __forceinline__ void gload_lds16(const void* gp, void* lp) {
    __builtin_amdgcn_global_load_lds((const AS1 void*)gp, (AS3 void*)lp, 16, 0, 0);
}

#if __has_builtin(__builtin_amdgcn_exp2f)
#define EXP2F(x) __builtin_amdgcn_exp2f(x)
#else
#define EXP2F(x) exp2f(x)
#endif

__device__ __forceinline__ uint32 rhu(float f) { return __float_as_uint(f) + 0x8000u; }
#if __has_builtin(__builtin_amdgcn_perm)
__device__ __forceinline__ uint32 pk2bf(float a, float b) {
    return __builtin_amdgcn_perm(rhu(b), rhu(a), 0x07060302u);
}
#else
__device__ __forceinline__ uint32 pk2bf(float a, float b) {
    return (rhu(a) >> 16) | (rhu(b) & 0xffff0000u);
}
#endif
__device__ __forceinline__ ushort_t f2bf(float f) { return (ushort_t)(rhu(f) >> 16); }

// gfx950 cross-lane row swaps (VALU, no LDS).
#if __has_builtin(__builtin_amdgcn_permlane32_swap)
__device__ __forceinline__ void plane32(uint32& a, uint32& b) {
    uint32x2 r = __builtin_amdgcn_permlane32_swap(a, b, false, false);
    a = r[0]; b = r[1];
}
#else
__device__ __forceinline__ void plane32(uint32& a, uint32& b) {
    asm("v_permlane32_swap_b32 %0, %1" : "+v"(a), "+v"(b));
}
#endif
#if __has_builtin(__builtin_amdgcn_permlane16_swap)
__device__ __forceinline__ void plane16(uint32& a, uint32& b) {
    uint32x2 r = __builtin_amdgcn_permlane16_swap(a, b, false, false);
    a = r[0]; b = r[1];
}
#else
__device__ __forceinline__ void plane16(uint32& a, uint32& b) {
    asm("v_permlane16_swap_b32 %0, %1" : "+v"(a), "+v"(b));
}
#endif

// ---------------- GEMM1: qkv = x·Wqkv^T (fp32 inputs, fused cvt) ----------------
// Tile 128(M)x192(N), BK=32, K=1024. Grid (16,32) = 512 blocks = 2/CU (full machine,
// cross-block overlap — the r6 ring's 192 blocks left 64 CUs idle at 1/CU).
// 256 thr = 4 waves, wave w owns cols [w*48, w*48+48), all 128 rows: acc[8][3].
// Staging: reg-staged fp32 loads (10 float4/thread/stage) + pk2bf + ds_write_b128 into
// the SAME XOR-chunk LDS layout as the verified readers: LDS[row][lc] holds global
// chunk lc ^ ((row>>1)&3). Schedule: single barrier per K-step, stage t+1 in regs
// during compute(t), written to the idle buffer after compute (T14 async-split).
// LDS 2x(8+12)KB = 40KB -> 2 blocks/CU. VGPR ~205 (<256 for 2 waves/SIMD).
__global__ __launch_bounds__(256, 2)
void gemm_qkv(const float* __restrict__ A, const float* __restrict__ B,
              ushort_t* __restrict__ Cb, ushort_t* __restrict__ vT, float qScale) {
    __shared__ ushort_t lA[2][128 * 32];
    __shared__ ushort_t lB[2][192 * 32];
    const int K = 1024;
    const int tid = threadIdx.x;
    const int wave = tid >> 6, lane = tid & 63;
    const int quad = lane >> 4, l16 = lane & 15;
    const int rsw = (l16 >> 1) & 3;

    // bijective XCD chunking: 512 blocks, 64/XCD (4 M-panels x all N per XCD -> A L2-resident)
    int bid = blockIdx.x + 16 * blockIdx.y;
    bid = (bid & 7) * 64 + (bid >> 3);
    const int nBase = (bid & 15) * 192, mBase = (bid >> 4) * 128;

    f32x4 acc[8][3];
#pragma unroll
    for (int i = 0; i < 8; i++)
#pragma unroll
        for (int j = 0; j < 3; j++) acc[i][j] = (f32x4){0.f, 0.f, 0.f, 0.f};

    // staging thread map: (row = p*64 + srow, LDS chunk = slc), global chunk gc = slc ^ rs
    const int srow = tid >> 2, slc = tid & 3;
    const int rs = (srow >> 1) & 3;      // ((p*64+srow)>>1)&3 == (srow>>1)&3 for all p
    const int gc = slc ^ rs;

    float4 ra[2][2], rb[3][2];           // stage-in-flight regs (named, static idx)

#define QLOAD(k0)                                                                     \
    {                                                                                 \
        _Pragma("unroll") for (int p = 0; p < 2; p++) {                               \
            const float* s = A + (size_t)(mBase + p * 64 + srow) * K + (k0) + gc * 8; \
            ra[p][0] = *(const float4*)(s);                                           \
            ra[p][1] = *(const float4*)(s + 4);                                       \
        }                                                                             \
        _Pragma("unroll") for (int p = 0; p < 3; p++) {                               \
            const float* s = B + (size_t)(nBase + p * 64 + srow) * K + (k0) + gc * 8; \
            rb[p][0] = *(const float4*)(s);                                           \
            rb[p][1] = *(const float4*)(s + 4);                                       \
        }                                                                             \
    }

#define QCVTW(buf)                                                                    \
    {                                                                                 \
        _Pragma("unroll") for (int p = 0; p < 2; p++) {                               \
            uint4 w;                                                                  \
            w.x = pk2bf(ra[p][0].x, ra[p][0].y); w.y = pk2bf(ra[p][0].z, ra[p][0].w); \
            w.z = pk2bf(ra[p][1].x, ra[p][1].y); w.w = pk2bf(ra[p][1].z, ra[p][1].w); \
            *(uint4*)(&lA[buf][(p * 64 + srow) * 32 + slc * 8]) = w;                  \
        }                                                                             \
        _Pragma("unroll") for (int p = 0; p < 3; p++) {                               \
            uint4 w;                                                                  \
            w.x = pk2bf(rb[p][0].x, rb[p][0].y); w.y = pk2bf(rb[p][0].z, rb[p][0].w); \
            w.z = pk2bf(rb[p][1].x, rb[p][1].y); w.w = pk2bf(rb[p][1].z, rb[p][1].w); \
            *(uint4*)(&lB[buf][(p * 64 + srow) * 32 + slc * 8]) = w;                  \
        }                                                                             \
    }

#define QCOMP(buf)                                                                    \
    {                                                                                 \
        short8 af[8], bf[3];                                                          \
        _Pragma("unroll") for (int i = 0; i < 8; i++)                                 \
            af[i] = *(const short8*)(&lA[buf][(i * 16 + l16) * 32 + ((quad ^ rsw) * 8)]); \
        _Pragma("unroll") for (int j = 0; j < 3; j++)                                 \
            bf[j] = *(const short8*)(&lB[buf][(wave * 48 + j * 16 + l16) * 32 +       \
                                              ((quad ^ rsw) * 8)]);                   \
        _Pragma("unroll") for (int i = 0; i < 8; i++)                                 \
            _Pragma("unroll") for (int j = 0; j < 3; j++)                             \
                acc[i][j] = __builtin_amdgcn_mfma_f32_16x16x32_bf16(af[i], bf[j],     \
                                                                    acc[i][j], 0, 0, 0); \
    }

    // prologue: stage 0 into buf0, issue stage 1 loads
    QLOAD(0);
    QCVTW(0);            // compiler inserts vmcnt waits on ra/rb data deps
    QLOAD(32);
    __syncthreads();

    for (int t = 0; t < 32; ++t) {
        const int buf = t & 1;
        QCOMP(buf);                       // reads stage t
        if (t < 31) {
            QCVTW(buf ^ 1);               // writes stage t+1 (idle buffer; all waves
                                          // finished reading it before last barrier)
            if (t < 30) QLOAD((t + 2) * 32);
        }
        __syncthreads();                  // stage t+1 visible; nobody still reads buf
    }

    // ---- epilogue: cols [0,2048) -> qk bf16 (Q scaled); [2048,3072) -> V^T ----
#pragma unroll
    for (int i = 0; i < 8; i++)
#pragma unroll
        for (int j = 0; j < 3; j++) {
            const int colBase = nBase + wave * 48 + j * 16;
            const int row0 = mBase + i * 16 + quad * 4;
            if (colBase >= 2048) {
                const int col = colBase + l16 - 2048;
                const int b = row0 >> 11, s0 = row0 & 2047;
                uint2 pk;
                pk.x = pk2bf(acc[i][j][0], acc[i][j][1]);
                pk.y = pk2bf(acc[i][j][2], acc[i][j][3]);
                *(uint2*)(vT + ((size_t)(b * 16) * 64 + col) * 2048 + s0) = pk;
            } else {
                const float cs = (colBase < 1024) ? qScale : 1.0f;
                const int col = colBase + l16;
#pragma unroll
                for (int r = 0; r < 4; r++)
                    Cb[(size_t)(row0 + r) * 2048 + col] = f2bf(acc[i][j][r] * cs);
            }
        }
}

// ---------------- GEMM2: out = o·Wout^T + bias (fp32 Wout, fused cvt) ----------------
// 64x128 tile, BK=64, K=1024, grid (8,64) = 512 blocks = 2/CU. Dispatch pins XCD = x%8 ->
// each XCD's 512KB Wout panel is L2-resident. Fully reg-staged dbuf (A bf16 pass-through,
// B fp32 -> pk2bf), single barrier per K-step, same proof as gemm_qkv.
__global__ __launch_bounds__(256, 2)
void gemm_out(const ushort_t* __restrict__ A, const float* __restrict__ B,
              float* __restrict__ Cf, const float* __restrict__ bias) {
    const int K = 1024, N = 1024;
    __shared__ ushort_t lA[2][64 * 64];
    __shared__ ushort_t lB[2][128 * 64];
    const int tid = threadIdx.x;
    const int wave = tid >> 6, lane = tid & 63;
    const int quad = lane >> 4, l16 = lane & 15;
    const int swz = l16 & 7;
    const int mBase = blockIdx.y * 64, nBase = blockIdx.x * 128;

    f32x4 acc[4][2];
#pragma unroll
    for (int i = 0; i < 4; i++)
#pragma unroll
        for (int j = 0; j < 2; j++) acc[i][j] = (f32x4){0.f, 0.f, 0.f, 0.f};

    // staging map: (row = p*32 + srow, LDS chunk lc = tid&7), gc = lc ^ (srow&7)
    const int srow = tid >> 3, slc = tid & 7;
    const int gc = slc ^ (srow & 7);

    short8 ra2[2];        // A bf16 pass-through (2 x 16B/stage)
    float4 rb[4][2];      // B fp32 (8 float4/stage)

#define OLOAD(k0)                                                                     \
    {                                                                                 \
        _Pragma("unroll") for (int c = 0; c < 2; c++)                                 \
            ra2[c] = *(const short8*)(A + (size_t)(mBase + c * 32 + srow) * K +       \
                                      (k0) + gc * 8);                                 \
        _Pragma("unroll") for (int p = 0; p < 4; p++) {                               \
            const float* s = B + (size_t)(nBase + p * 32 + srow) * K + (k0) + gc * 8; \
            rb[p][0] = *(const float4*)(s);                                           \
            rb[p][1] = *(const float4*)(s + 4);                                       \
        }                                                                             \
    }

#define OCVTW(buf)                                                                    \
    {                                                                                 \
        _Pragma("unroll") for (int c = 0; c < 2; c++)                                 \
            *(short8*)(&lA[buf][(c * 32 + srow) * 64 + slc * 8]) = ra2[c];            \
        _Pragma("unroll") for (int p = 0; p < 4; p++) {                               \
            uint4 w;                                                                  \
            w.x = pk2bf(rb[p][0].x, rb[p][0].y); w.y = pk2bf(rb[p][0].z, rb[p][0].w); \
            w.z = pk2bf(rb[p][1].x, rb[p][1].y); w.w = pk2bf(rb[p][1].z, rb[p][1].w); \
            *(uint4*)(&lB[buf][(p * 32 + srow) * 64 + slc * 8]) = w;                  \
        }                                                                             \
    }

#define OCOMP(buf)                                                                    \
    _Pragma("unroll") for (int ks = 0; ks < 2; ks++) {                                \
        short8 af[4], bf[2];                                                          \
        _Pragma("unroll") for (int i = 0; i < 4; i++)                                 \
            af[i] = *(const short8*)(&lA[buf][(i * 16 + l16) * 64 +                   \
                                              (((ks * 4 + quad) ^ swz) * 8)]);        \
        _Pragma("unroll") for (int j = 0; j < 2; j++)                                 \
            bf[j] = *(const short8*)(&lB[buf][(wave * 32 + j * 16 + l16) * 64 +       \
                                              (((ks * 4 + quad) ^ swz) * 8)]);        \
        _Pragma("unroll") for (int i = 0; i < 4; i++)                                 \
            _Pragma("unroll") for (int j = 0; j < 2; j++)                             \
                acc[i][j] = __builtin_amdgcn_mfma_f32_16x16x32_bf16(af[i], bf[j],     \
                                                                    acc[i][j], 0, 0, 0); \
    }

    OLOAD(0);
    OCVTW(0);
    OLOAD(64);
    __syncthreads();

    for (int t = 0; t < 16; ++t) {
        const int buf = t & 1;
        OCOMP(buf);
        if (t < 15) {
            OCVTW(buf ^ 1);
            if (t < 14) OLOAD((t + 2) * 64);
        }
        __syncthreads();
    }

#pragma unroll
    for (int i = 0; i < 4; i++)
#pragma unroll
        for (int j = 0; j < 2; j++)
#pragma unroll
            for (int r = 0; r < 4; r++) {
                const int row = mBase + i * 16 + quad * 4 + r;
                const int col = nBase + wave * 32 + j * 16 + l16;
                Cf[(size_t)row * N + col] = acc[i][j][r] + bias[col];
            }
}

// ---------------- fused flash attention (verified r4/r6, ~47us) ----------------
// 512 thr = 8 waves = 4 qg x 2 kg; Bq=128, wave owns 32 q x 32 keys of each 64-key tile.
// grid (32,16): x=bh -> XCD = bh%8: all 16 blocks of one (b,h) share an XCD L2 (FETCH -82%).
// P never touches LDS: exp2+pk2bf+permlane32/16 rebuild the PV B-frag in registers
// (bank conflicts = 0). K dbuf 2x8KB, V 3-buf 3x8KB. 56KB -> 2 blocks/CU.
__global__ __launch_bounds__(512, 4)
void attn_flash(const ushort_t* __restrict__ qk, const ushort_t* __restrict__ vT,
                ushort_t* __restrict__ o) {
    __shared__ ushort_t smem[28672];

    const int tid = threadIdx.x;
    const int wave = tid >> 6, lane = tid & 63;
    const int quad = lane >> 4, l16 = lane & 15;
    const int qg = wave & 3, kg = wave >> 2;
    const int bh = blockIdx.x, b = bh >> 4, h = bh & 15;
    const size_t rowBase = (size_t)b * 2048;
    const int qCol = h * 64, kCol = 1024 + h * 64;
    const int qRow0 = blockIdx.y * 128;
    const int swz = l16 & 7;

    const int sr = tid >> 3;                       // 0..63
    const int sc = ((tid & 7) ^ (sr & 7)) * 8;

#pragma unroll
    for (int cc = 0; cc < 2; cc++)
        gload_lds16(qk + (rowBase + qRow0 + cc * 64 + sr) * 2048 + qCol + sc,
                    smem + 20480 + cc * 4096 + wave * 512);
    __syncthreads();
    short8 qf[2][2];  // [qt][ks]: q = qg*32 + qt*16 + l16
#pragma unroll
    for (int qt = 0; qt < 2; qt++)
#pragma unroll
        for (int ks = 0; ks < 2; ks++)
            qf[qt][ks] = *(const short8*)(smem + 20480 + (qg * 32 + qt * 16 + l16) * 64 +
                                          (((ks * 4 + quad) ^ swz) * 8));

    short8 onesA;
#pragma unroll
    for (int i = 0; i < 8; i++) onesA[i] = (short)0x3F80;

    f32x4 oacc[4][2];
    f32x4 lacc[2];
#pragma unroll
    for (int qt = 0; qt < 2; qt++) {
        lacc[qt] = (f32x4){0.f, 0.f, 0.f, 0.f};
#pragma unroll
        for (int dt = 0; dt < 4; dt++) oacc[dt][qt] = (f32x4){0.f, 0.f, 0.f, 0.f};
    }

    const ushort_t* kptr = qk + (rowBase + sr) * 2048 + kCol + sc;
    const ushort_t* vptr = vT + ((size_t)bh * 64 + sr) * 2048 + sc;

    f32x4 sacc[2][2];
    short8 pfA[2], pfB[2];

#define AT_STAGE(kbi, vbi, kt)                                                         \
    {                                                                                  \
        gload_lds16(kptr + (size_t)((kt) * 64) * 2048, smem + (kbi) * 4096 + wave * 512); \
        gload_lds16(vptr + (kt) * 64, smem + 8192 + (vbi) * 4096 + wave * 512);        \
    }

#define S_BLOCK(cur)                                                                   \
    {                                                                                  \
        const ushort_t* lK = smem + (cur) * 4096;                                      \
        _Pragma("unroll") for (int mh = 0; mh < 2; mh++) {                             \
            const int krow = kg * 32 + mh * 16 + l16;                                  \
            const short8 k0 = *(const short8*)(lK + krow * 64 + ((quad ^ swz) * 8));   \
            const short8 k1 = *(const short8*)(lK + krow * 64 + (((4 + quad) ^ swz) * 8)); \
            __builtin_amdgcn_s_setprio(1);                                             \
            _Pragma("unroll") for (int qt = 0; qt < 2; qt++) {                         \
                f32x4 t = (f32x4){0.f, 0.f, 0.f, 0.f};                                 \
                t = __builtin_amdgcn_mfma_f32_16x16x32_bf16(k0, qf[qt][0], t, 0, 0, 0); \
                t = __builtin_amdgcn_mfma_f32_16x16x32_bf16(k1, qf[qt][1], t, 0, 0, 0); \
                sacc[mh][qt] = t;                                                      \
            }                                                                          \
            __builtin_amdgcn_s_setprio(0);                                             \
        }                                                                              \
    }

#define EXPPK_BLOCK(pfdst)                                                             \
    _Pragma("unroll") for (int qt = 0; qt < 2; qt++) {                                 \
        uint32 a0 = pk2bf(EXP2F(sacc[0][qt][0]), EXP2F(sacc[0][qt][1]));               \
        uint32 a1 = pk2bf(EXP2F(sacc[0][qt][2]), EXP2F(sacc[0][qt][3]));               \
        uint32 b0 = pk2bf(EXP2F(sacc[1][qt][0]), EXP2F(sacc[1][qt][1]));               \
        uint32 b1 = pk2bf(EXP2F(sacc[1][qt][2]), EXP2F(sacc[1][qt][3]));               \
        plane32(a0, b0); plane16(a0, b0);                                              \
        plane32(a1, b1); plane16(a1, b1);                                              \
        union { uint32 u[4]; short8 s; } w_;                                           \
        w_.u[0] = a0; w_.u[1] = a1; w_.u[2] = b0; w_.u[3] = b1;                        \
        pfdst[qt] = w_.s;                                                              \
    }

#define PV_BLOCK(vbi, pf)                                                              \
    {                                                                                  \
        const ushort_t* lV = smem + 8192 + (vbi) * 4096;                               \
        _Pragma("unroll") for (int qt = 0; qt < 2; qt++)                               \
            lacc[qt] = __builtin_amdgcn_mfma_f32_16x16x32_bf16(onesA, pf[qt], lacc[qt], 0, 0, 0); \
        __builtin_amdgcn_s_setprio(1);                                                 \
        _Pragma("unroll") for (int dt = 0; dt < 4; dt++) {                             \
            const short8 vf = *(const short8*)(lV + (dt * 16 + l16) * 64 +             \
                                               (((kg * 4 + quad) ^ swz) * 8));         \
            _Pragma("unroll") for (int qt = 0; qt < 2; qt++)                           \
                oacc[dt][qt] = __builtin_amdgcn_mfma_f32_16x16x32_bf16(vf, pf[qt], oacc[dt][qt], 0, 0, 0); \
        }                                                                              \
        __builtin_amdgcn_s_setprio(0);                                                 \
    }

    AT_STAGE(0, 0, 0);

    __syncthreads();
    AT_STAGE(1, 1, 1);
    S_BLOCK(0);
    EXPPK_BLOCK(pfA);

    int vs = 2, vp = 0;
    for (int kt = 1; kt <= 29; kt += 2) {
        __syncthreads();
        AT_STAGE(0, vs, kt + 1);
        S_BLOCK(1);
        PV_BLOCK(vp, pfA);
        EXPPK_BLOCK(pfB);
        vs = (vs == 2) ? 0 : vs + 1;
        vp = (vp == 2) ? 0 : vp + 1;
        __syncthreads();
        AT_STAGE(1, vs, kt + 2);
        S_BLOCK(0);
        PV_BLOCK(vp, pfB);
        EXPPK_BLOCK(pfA);
        vs = (vs == 2) ? 0 : vs + 1;
        vp = (vp == 2) ? 0 : vp + 1;
    }

    __syncthreads();
    S_BLOCK(1);
    PV_BLOCK(0, pfA);
    EXPPK_BLOCK(pfB);
    PV_BLOCK(1, pfB);

    __syncthreads();
    float* red = (float*)smem;
    if (kg == 1) {
#pragma unroll
        for (int qt = 0; qt < 2; qt++) {
            if (quad == 0) red[8192 + qg * 32 + qt * 16 + l16] = lacc[qt][0];
#pragma unroll
            for (int dt = 0; dt < 4; dt++)
                *(f32x4*)(red + (((qg * 4 + dt) * 2 + qt) * 64 + lane) * 4) = oacc[dt][qt];
        }
    }
    __syncthreads();
    if (kg == 0) {
        float linv[2];
#pragma unroll
        for (int qt = 0; qt < 2; qt++)
            linv[qt] = 1.0f / (lacc[qt][0] + red[8192 + qg * 32 + qt * 16 + l16]);
#pragma unroll
        for (int qt = 0; qt < 2; qt++) {
            const size_t row = rowBase + qRow0 + qg * 32 + qt * 16 + l16;
#pragma unroll
            for (int dt = 0; dt < 4; dt++) {
                const f32x4 r = *(const f32x4*)(red + (((qg * 4 + dt) * 2 + qt) * 64 + lane) * 4);
                uint2 pk;
                pk.x = pk2bf((oacc[dt][qt][0] + r[0]) * linv[qt],
                             (oacc[dt][qt][1] + r[1]) * linv[qt]);
                pk.y = pk2bf((oacc[dt][qt][2] + r[2]) * linv[qt],
                             (oacc[dt][qt][3] + r[3]) * linv[qt]);
                *(uint2*)(o + row * 1024 + h * 64 + dt * 16 + quad * 4) = pk;
            }
        }
    }
}

extern "C" void kernel_launch(void* const* d_in, const int* in_sizes, int n_in,
                              void* d_out, int out_size, void* d_ws, size_t ws_size,
                              hipStream_t stream) {
    const float* x    = (const float*)d_in[0];
    const float* Wqkv = (const float*)d_in[1];
    const float* Wout = (const float*)d_in[2];
    const float* bout = (const float*)d_in[3];
    float* out = (float*)d_out;

    ushort_t* qkb = (ushort_t*)d_ws;                       // 4096*2048 (Q*SC, K)
    ushort_t* vTb = qkb + (size_t)4096 * 2048;             // 32*64*2048 (V^T)
    ushort_t* ob  = vTb + (size_t)32 * 64 * 2048;          // 4096*1024 (attn out)

    const float SC = 0.125f * 1.44269504089f;  // SCALE * log2(e)

    // 3 launches (cvt fused into both GEMMs)
    gemm_qkv<<<dim3(16, 32), 256, 0, stream>>>(x, Wqkv, qkb, vTb, SC);
    attn_flash<<<dim3(32, 16), 512, 0, stream>>>(qkb, vTb, ob);
    gemm_out<<<dim3(8, 64), 256, 0, stream>>>(ob, Wout, out, bout);
}